// Round 1
// baseline (9085.751 us; speedup 1.0000x reference)
//
#include <hip/hip_runtime.h>

#define HD 1024
#define VOC 32000
#define SL 64
#define TL 64
#define NWG 256
#define BLK 256

// ---- workspace float offsets ----
#define OFF_H      64        // h double buffer: 2*1024
#define OFF_ENCO   4096      // enc_outs [64][1024]
#define OFF_EPT    69632     // epT [1024][64]  (enc_proj transposed)
#define OFF_WIHX   135168    // WihX [64][4096] (enc_Wih@x + bih + bhh)
#define OFF_Q      397312    // Q    [64][4096]
#define OFF_M1     659456    // M1   [64][1024] ([s][j] = W1c[j].enc_outs[s])
#define OFF_M2     724992    // M2T  [64][4096] ([s][r])
#define OFF_PE     987136    // part_e [64][64]
#define OFF_H2     991232    // H2   [64][1024]
#define OFF_PRET   1056768   // PreT [1024][64]
#define OFF_XENC   1122304   // Xenc [64][1024] f32
#define OFF_XDEC   1187840   // Xdec [64][1024] f32
#define OFF_PRE1   1253376   // pre1 [64][1024]

struct KArgs {
  const int* src; const int* tgt;
  const void *enc_emb, *enc_Wih, *enc_Whh, *enc_bih, *enc_bhh;
  const void *dec_emb, *att_We, *att_be, *att_Wu, *att_bu, *att_v;
  const void *w1_W, *w1_b, *w2_W, *w2_b;
  const void *dec_Wih, *dec_Whh, *dec_bih, *dec_bhh;
  const void *out_W, *out_b;
  void* out; float* ws;
};

__device__ __forceinline__ float bf2f(unsigned short u) {
  unsigned w = ((unsigned)u) << 16; float f; __builtin_memcpy(&f, &w, 4); return f;
}
__device__ __forceinline__ unsigned short f2bf(float f) {
  unsigned u; __builtin_memcpy(&u, &f, 4);
  unsigned r = u + 0x7FFFu + ((u >> 16) & 1u);
  return (unsigned short)(r >> 16);
}
__device__ __forceinline__ float sigmf(float x) { return 1.f / (1.f + expf(-x)); }

struct BFT {}; struct FPT {};
template<class DT> struct LD;
template<> struct LD<FPT> {
  static __device__ __forceinline__ float get(const void* p, long i) { return ((const float*)p)[i]; }
};
template<> struct LD<BFT> {
  static __device__ __forceinline__ float get(const void* p, long i) { return bf2f(((const unsigned short*)p)[i]); }
};
template<class DT> struct LD4;
template<> struct LD4<FPT> {
  static __device__ __forceinline__ float4 get(const void* p, long i) {
    return *(const float4*)((const float*)p + i);
  }
};
template<> struct LD4<BFT> {
  static __device__ __forceinline__ float4 get(const void* p, long i) {
    ushort4 u = *(const ushort4*)((const unsigned short*)p + i);
    float4 f; f.x = bf2f(u.x); f.y = bf2f(u.y); f.z = bf2f(u.z); f.w = bf2f(u.w); return f;
  }
};
template<class DT> struct ST;
template<> struct ST<FPT> {
  static __device__ __forceinline__ void put(void* p, long i, float v) { ((float*)p)[i] = v; }
};
template<> struct ST<BFT> {
  static __device__ __forceinline__ void put(void* p, long i, float v) { ((unsigned short*)p)[i] = f2bf(v); }
};

// ---- tree grid barrier: 8 groups of 32 -> root -> flag (monotonic epochs) ----
// ws_u[8..15]: group counters, ws_u[16]: root, ws_u[20]: release flag
__device__ __forceinline__ void gbar(unsigned* ws_u, unsigned* ep, int tid, int wg) {
  __syncthreads();
  if (tid == 0) {
    unsigned e = ++(*ep);
    __threadfence();
    unsigned old = __hip_atomic_fetch_add(&ws_u[8 + (wg >> 5)], 1u,
                                          __ATOMIC_ACQ_REL, __HIP_MEMORY_SCOPE_AGENT);
    if (old == e * 32u - 1u) {
      unsigned o2 = __hip_atomic_fetch_add(&ws_u[16], 1u,
                                           __ATOMIC_ACQ_REL, __HIP_MEMORY_SCOPE_AGENT);
      if (o2 == e * 8u - 1u) {
        __hip_atomic_store(&ws_u[20], e, __ATOMIC_RELEASE, __HIP_MEMORY_SCOPE_AGENT);
      }
    }
    while (__hip_atomic_load(&ws_u[20], __ATOMIC_ACQUIRE, __HIP_MEMORY_SCOPE_AGENT) < e) {
      __builtin_amdgcn_s_sleep(2);
    }
    __threadfence();
  }
  __syncthreads();
}

// out[t][r] (or [r][t] if TRO) = sum_k W[r*wstride+woff+k] (* + woff2 half if DUAL) * X[t*HD+k] (+biases)
// rows r0..r0+NR-1, 64 "t" rows of X. NR in {4,16}.
template<class DT, int NR, bool DUAL, bool TRO>
__device__ void gemm_rows(const void* W, int wstride, int woff, int woff2,
                          int r0, const float* X, float* out, int ostride,
                          const void* b1, const void* b2, int tid, float* s_stage) {
  const int PER = NR / 4;
  float acc[PER];
#pragma unroll
  for (int i = 0; i < PER; ++i) acc[i] = 0.f;
  for (int k0 = 0; k0 < HD; k0 += 128) {
    __syncthreads();
    for (int i = tid; i < 64 * 128; i += BLK) {
      int t = i >> 7, kk = i & 127;
      s_stage[t * 129 + kk] = X[t * HD + k0 + kk];
    }
    __syncthreads();
#pragma unroll
    for (int i = 0; i < PER; ++i) {
      int oi = tid + i * BLK;
      int t = oi & 63, r_l = oi >> 6;
      long r = r0 + r_l;
      long wb = r * wstride + woff + k0;
      long wb2 = r * wstride + woff2 + k0;
      float a = 0.f;
#pragma unroll 8
      for (int kk = 0; kk < 128; kk += 4) {
        float4 wv = LD4<DT>::get(W, wb + kk);
        if (DUAL) {
          float4 w2 = LD4<DT>::get(W, wb2 + kk);
          wv.x += w2.x; wv.y += w2.y; wv.z += w2.z; wv.w += w2.w;
        }
        a += wv.x * s_stage[t * 129 + kk]     + wv.y * s_stage[t * 129 + kk + 1]
           + wv.z * s_stage[t * 129 + kk + 2] + wv.w * s_stage[t * 129 + kk + 3];
      }
      acc[i] += a;
    }
  }
  __syncthreads();
#pragma unroll
  for (int i = 0; i < PER; ++i) {
    int oi = tid + i * BLK;
    int t = oi & 63, r_l = oi >> 6;
    int r = r0 + r_l;
    float v = acc[i];
    if (b1) v += LD<DT>::get(b1, r);
    if (b2) v += LD<DT>::get(b2, r);
    if (TRO) out[r * ostride + t] = v; else out[t * ostride + r] = v;
  }
}

template<class DT>
__device__ void run_all(const KArgs& A, int tid, int wg,
                        float* s_stage, float* s_red, float* s_w, float* s_m2,
                        float* s_whh, float* s_wh, float* s_gate, float* s_c) {
  float* ws = A.ws;
  unsigned* ws_u = (unsigned*)ws;
  unsigned epoch = 0;
  float* h     = ws + OFF_H;
  float* enc_o = ws + OFF_ENCO;
  float* epT   = ws + OFF_EPT;
  float* WihX  = ws + OFF_WIHX;
  float* Q     = ws + OFF_Q;
  float* M1    = ws + OFF_M1;
  float* M2T   = ws + OFF_M2;
  float* pe_g  = ws + OFF_PE;
  float* H2    = ws + OFF_H2;
  float* PreT  = ws + OFF_PRET;
  float* Xenc  = ws + OFF_XENC;
  float* Xdec  = ws + OFF_XDEC;
  float* pre1  = ws + OFF_PRE1;
  const int j0 = wg * 4;

  // ---- P0a: embedding gathers, zero h/c ----
  if (tid < 4) { s_c[tid] = 0.f; h[j0 + tid] = 0.f; }
  if (wg < 64) {
    int t = wg, tok = A.src[t];
    for (int k = tid; k < HD; k += BLK) Xenc[t * HD + k] = LD<DT>::get(A.enc_emb, (long)tok * HD + k);
  } else if (wg < 128) {
    int t = wg - 64;
    int tok = (t == 0) ? 0 : A.tgt[t - 1];
    for (int k = tid; k < HD; k += BLK) Xdec[t * HD + k] = LD<DT>::get(A.dec_emb, (long)tok * HD + k);
  }
  gbar(ws_u, &epoch, tid, wg);

  // ---- P0b: WihX (enc_Wih@x + bih + bhh), pre1 (W1x@x + w1_b) ----
  gemm_rows<DT, 16, false, false>(A.enc_Wih, 1024, 0, 0, wg * 16, Xenc, WihX, 4096,
                                  A.enc_bih, A.enc_bhh, tid, s_stage);
  gemm_rows<DT, 4, false, false>(A.w1_W, 2048, 1024, 0, wg * 4, Xdec, pre1, 1024,
                                 A.w1_b, nullptr, tid, s_stage);
  gbar(ws_u, &epoch, tid, wg);

  // ---- encoder loop ----
  const int row_l = tid >> 4, lane = tid & 15;
  const int gg_ = row_l >> 2, qq_ = row_l & 3;
  const int myrow = gg_ * 1024 + j0 + qq_;
  for (int t = 0; t < SL; ++t) {
    const float* hb = h + (t & 1) * HD;
    float* hb2 = h + ((t + 1) & 1) * HD;
    float part = 0.f;
#pragma unroll 4
    for (int j = 0; j < 16; ++j) {
      int k = (lane << 2) + (j << 6);
      float4 wv = LD4<DT>::get(A.enc_Whh, (long)myrow * HD + k);
      const float4 hv = *(const float4*)(hb + k);
      part += wv.x * hv.x + wv.y * hv.y + wv.z * hv.z + wv.w * hv.w;
    }
    s_red[tid] = part;
    __syncthreads();
    if (tid < 16) {
      float v = 0.f;
      for (int i = 0; i < 16; ++i) v += s_red[tid * 16 + i];
      int rr = (tid >> 2) * 1024 + j0 + (tid & 3);
      s_gate[tid] = v + WihX[t * 4096 + rr];
    }
    __syncthreads();
    if (tid < 4) {
      float ig = s_gate[tid], fg = s_gate[4 + tid], gv = s_gate[8 + tid], og = s_gate[12 + tid];
      float c2 = sigmf(fg) * s_c[tid] + sigmf(ig) * tanhf(gv);
      float h2v = sigmf(og) * tanhf(c2);
      s_c[tid] = c2;
      hb2[j0 + tid] = h2v;
      enc_o[t * HD + j0 + tid] = h2v;
    }
    gbar(ws_u, &epoch, tid, wg);
  }

  // ---- P1ab: epT = (att_Wu@enc_outs + bu)^T ; M1[s][j] = W1c[j].enc_outs[s] ----
  gemm_rows<DT, 4, false, true>(A.att_Wu, 1024, 0, 0, wg * 4, enc_o, epT, 64,
                                A.att_bu, nullptr, tid, s_stage);
  gemm_rows<DT, 4, false, false>(A.w1_W, 2048, 0, 0, wg * 4, enc_o, M1, 1024,
                                 nullptr, nullptr, tid, s_stage);
  gbar(ws_u, &epoch, tid, wg);

  // ---- P1cd: M2T[s][r] = dec_Wih@M1 ; Q[t][r] = dec_Wih@pre1 + bih + bhh ----
  gemm_rows<DT, 16, false, false>(A.dec_Wih, 1024, 0, 0, wg * 16, M1, M2T, 4096,
                                  nullptr, nullptr, tid, s_stage);
  gemm_rows<DT, 16, false, false>(A.dec_Wih, 1024, 0, 0, wg * 16, pre1, Q, 4096,
                                  A.dec_bih, A.dec_bhh, tid, s_stage);
  gbar(ws_u, &epoch, tid, wg);

  // ---- P1e: copy my 16 M2 rows into LDS [16][65] ----
  for (int i = tid; i < 1024; i += BLK) {
    int l = i >> 6, s = i & 63;
    int r = (l >> 2) * 1024 + j0 + (l & 3);
    s_m2[l * 65 + s] = M2T[s * 4096 + r];
  }

  // ---- decoder loop ----
  for (int t = 0; t < TL; ++t) {
    const float* hb = h + (t & 1) * HD;
    float* hb2 = h + ((t + 1) & 1) * HD;
    // phase A': Whh@h (all WGs), We@h + partial energies (WGs 0..63)
    {
      float part = 0.f;
#pragma unroll 4
      for (int j = 0; j < 16; ++j) {
        int k = (lane << 2) + (j << 6);
        float4 wv = LD4<DT>::get(A.dec_Whh, (long)myrow * HD + k);
        const float4 hv = *(const float4*)(hb + k);
        part += wv.x * hv.x + wv.y * hv.y + wv.z * hv.z + wv.w * hv.w;
      }
      s_red[tid] = part;
      __syncthreads();
      if (tid < 16) {
        float v = 0.f;
        for (int i = 0; i < 16; ++i) v += s_red[tid * 16 + i];
        s_whh[tid] = v;
      }
      __syncthreads();
      if (wg < 64) {
        int jr = wg * 16 + row_l;
        float p2 = 0.f;
#pragma unroll 4
        for (int j = 0; j < 16; ++j) {
          int k = (lane << 2) + (j << 6);
          float4 wv = LD4<DT>::get(A.att_We, (long)jr * HD + k);
          const float4 hv = *(const float4*)(hb + k);
          p2 += wv.x * hv.x + wv.y * hv.y + wv.z * hv.z + wv.w * hv.w;
        }
        s_red[tid] = p2;
        __syncthreads();
        if (tid < 16) {
          float v2 = 0.f;
          for (int i = 0; i < 16; ++i) v2 += s_red[tid * 16 + i];
          s_wh[tid] = v2 + LD<DT>::get(A.att_be, wg * 16 + tid);
        }
        __syncthreads();
        if (tid < 64) {
          int s = tid;
          float pe = 0.f;
#pragma unroll
          for (int jj = 0; jj < 16; ++jj) {
            int jg = wg * 16 + jj;
            float arg = s_wh[jj] + epT[jg * 64 + s];
            pe += LD<DT>::get(A.att_v, jg) * tanhf(arg);
          }
          pe_g[wg * 64 + s] = pe;
        }
      }
    }
    gbar(ws_u, &epoch, tid, wg);
    // phase C: reduce energies, softmax, gates, elementwise
    {
      int s = tid & 63, gb = tid >> 6;
      float pe = 0.f;
      for (int g2 = gb * 16; g2 < gb * 16 + 16; ++g2) pe += pe_g[g2 * 64 + s];
      s_red[tid] = pe;
      __syncthreads();
      if (tid < 64) s_w[tid] = s_red[tid] + s_red[64 + tid] + s_red[128 + tid] + s_red[192 + tid];
      __syncthreads();
      if (tid == 0) {
        float m = s_w[0];
        for (int i = 1; i < 64; ++i) m = fmaxf(m, s_w[i]);
        s_red[0] = m;
      }
      __syncthreads();
      if (tid < 64) s_w[tid] = expf(s_w[tid] - s_red[0]);
      __syncthreads();
      if (tid == 0) {
        float sum = 0.f;
        for (int i = 0; i < 64; ++i) sum += s_w[i];
        s_red[0] = 1.f / sum;
      }
      __syncthreads();
      if (tid < 16) {
        int r = (tid >> 2) * 1024 + j0 + (tid & 3);
        float ctx = 0.f;
#pragma unroll 8
        for (int s2 = 0; s2 < 64; ++s2) ctx += s_m2[tid * 65 + s2] * s_w[s2];
        s_gate[tid] = s_whh[tid] + Q[t * 4096 + r] + ctx * s_red[0];
      }
      __syncthreads();
      if (tid < 4) {
        float ig = s_gate[tid], fg = s_gate[4 + tid], gv = s_gate[8 + tid], og = s_gate[12 + tid];
        float c2 = sigmf(fg) * s_c[tid] + sigmf(ig) * tanhf(gv);
        float h2v = sigmf(og) * tanhf(c2);
        s_c[tid] = c2;
        hb2[j0 + tid] = h2v;
        H2[t * HD + j0 + tid] = h2v;
      }
    }
    gbar(ws_u, &epoch, tid, wg);
  }

  // ---- P2: PreT[j][t] = (w2[:, :H]+w2[:, H:])@H2 + w2_b ----
  gemm_rows<DT, 4, true, true>(A.w2_W, 2048, 0, 1024, wg * 4, H2, PreT, 64,
                               A.w2_b, nullptr, tid, s_stage);
  gbar(ws_u, &epoch, tid, wg);

  // ---- P3: logits[t][v] = out_W[v].Pre[t] + out_b[v] ----
  {
    const int t = tid & 63, kq = tid >> 6;
    const int kb = kq << 8;
    for (int i = 0; i < 125; ++i) {
      int v = wg + (i << 8);
      long wbase = (long)v * HD + kb;
      float a = 0.f;
#pragma unroll 8
      for (int k = 0; k < 256; k += 4) {
        float4 wv = LD4<DT>::get(A.out_W, wbase + k);
        a += wv.x * PreT[(kb + k) * 64 + t]     + wv.y * PreT[(kb + k + 1) * 64 + t]
           + wv.z * PreT[(kb + k + 2) * 64 + t] + wv.w * PreT[(kb + k + 3) * 64 + t];
      }
      s_red[tid] = a;
      __syncthreads();
      if (tid < 64) {
        float r2 = s_red[tid] + s_red[64 + tid] + s_red[128 + tid] + s_red[192 + tid]
                 + LD<DT>::get(A.out_b, v);
        ST<DT>::put(A.out, (long)tid * VOC + v, r2);
      }
      __syncthreads();
    }
  }
}

__global__ __launch_bounds__(BLK)
void lstm_seq2seq_kernel(KArgs A) {
  __shared__ float s_stage[64 * 129];
  __shared__ float s_red[BLK];
  __shared__ float s_w[64];
  __shared__ float s_m2[16 * 65];
  __shared__ float s_whh[16];
  __shared__ float s_wh[16];
  __shared__ float s_gate[16];
  __shared__ float s_c[4];
  __shared__ int s_flag;

  const int tid = threadIdx.x, wg = blockIdx.x;

  // dtype probe: bf16 pairs -> low-16 bits look like a bf16 with plausible exponent
  {
    const unsigned* pw = (const unsigned*)A.enc_Wih;
    int hits = 0;
    for (int i = tid; i < 4096; i += BLK) {
      unsigned ex = (pw[i] >> 7) & 0xFFu;
      hits += (ex >= 100u && ex <= 126u) ? 1 : 0;
    }
    s_red[tid] = (float)hits;
    __syncthreads();
    for (int s = BLK / 2; s > 0; s >>= 1) {
      if (tid < s) s_red[tid] += s_red[tid + s];
      __syncthreads();
    }
    if (tid == 0) s_flag = (s_red[0] > 2048.0f) ? 1 : 0;
    __syncthreads();
  }

  if (s_flag) run_all<BFT>(A, tid, wg, s_stage, s_red, s_w, s_m2, s_whh, s_wh, s_gate, s_c);
  else        run_all<FPT>(A, tid, wg, s_stage, s_red, s_w, s_m2, s_whh, s_wh, s_gate, s_c);
}

extern "C" void kernel_launch(void* const* d_in, const int* in_sizes, int n_in,
                              void* d_out, int out_size, void* d_ws, size_t ws_size,
                              hipStream_t stream) {
  (void)in_sizes; (void)n_in; (void)out_size; (void)ws_size;
  // zero barrier counters/flag (ws is poisoned 0xAA before every launch)
  hipMemsetAsync(d_ws, 0, 256, stream);
  KArgs a;
  a.src = (const int*)d_in[0];
  a.tgt = (const int*)d_in[1];
  a.enc_emb = d_in[3]; a.enc_Wih = d_in[4]; a.enc_Whh = d_in[5];
  a.enc_bih = d_in[6]; a.enc_bhh = d_in[7];
  a.dec_emb = d_in[8]; a.att_We = d_in[9]; a.att_be = d_in[10];
  a.att_Wu = d_in[11]; a.att_bu = d_in[12]; a.att_v = d_in[13];
  a.w1_W = d_in[14]; a.w1_b = d_in[15]; a.w2_W = d_in[16]; a.w2_b = d_in[17];
  a.dec_Wih = d_in[18]; a.dec_Whh = d_in[19]; a.dec_bih = d_in[20]; a.dec_bhh = d_in[21];
  a.out_W = d_in[22]; a.out_b = d_in[23];
  a.out = d_out; a.ws = (float*)d_ws;
  hipLaunchKernelGGL(lstm_seq2seq_kernel, dim3(NWG), dim3(BLK), 0, stream, a);
}

// Round 2
// 3521.037 us; speedup vs baseline: 2.5804x; 2.5804x over previous
//
#include <hip/hip_runtime.h>

#define HD 1024
#define VOC 32000
#define SL 64
#define TL 64
#define NWG 256
#define BLK 256

// ---- workspace float offsets ----
#define OFF_H      64        // h double buffer: 2*1024
#define OFF_ENCO   4096      // enc_outs [64][1024]
#define OFF_EPT    69632     // epT [1024][64]  (enc_proj transposed)
#define OFF_WIHX   135168    // WihX [64][4096] (enc_Wih@x + bih + bhh)
#define OFF_Q      397312    // Q    [64][4096]
#define OFF_M1     659456    // M1   [64][1024] ([s][j] = W1c[j].enc_outs[s])
#define OFF_M2     724992    // M2T  [64][4096] ([s][r])
#define OFF_PE     987136    // part_e [64][64]
#define OFF_H2     991232    // H2   [64][1024]
#define OFF_PRET   1056768   // PreT [1024][64]
#define OFF_XENC   1122304   // Xenc [64][1024] f32
#define OFF_XDEC   1187840   // Xdec [64][1024] f32
#define OFF_PRE1   1253376   // pre1 [64][1024]

struct KArgs {
  const int* src; const int* tgt;
  const void *enc_emb, *enc_Wih, *enc_Whh, *enc_bih, *enc_bhh;
  const void *dec_emb, *att_We, *att_be, *att_Wu, *att_bu, *att_v;
  const void *w1_W, *w1_b, *w2_W, *w2_b;
  const void *dec_Wih, *dec_Whh, *dec_bih, *dec_bhh;
  const void *out_W, *out_b;
  void* out; float* ws;
};

__device__ __forceinline__ float bf2f(unsigned short u) {
  unsigned w = ((unsigned)u) << 16; float f; __builtin_memcpy(&f, &w, 4); return f;
}
__device__ __forceinline__ unsigned short f2bf(float f) {
  unsigned u; __builtin_memcpy(&u, &f, 4);
  unsigned r = u + 0x7FFFu + ((u >> 16) & 1u);
  return (unsigned short)(r >> 16);
}
__device__ __forceinline__ float sigmf(float x) { return 1.f / (1.f + expf(-x)); }

// MALL-coherent (cross-XCD) relaxed accesses for all workspace traffic.
// Relaxed => no buffer_inv / buffer_wbl2 cache-maintenance ops are emitted;
// sc1 makes the access coherent at the Infinity Cache. Ordering w.r.t. the
// barrier comes from __syncthreads()'s vmcnt(0) drain + control dependence.
__device__ __forceinline__ float ldw(const float* p) {
  return __hip_atomic_load(p, __ATOMIC_RELAXED, __HIP_MEMORY_SCOPE_AGENT);
}
__device__ __forceinline__ void stw(float* p, float v) {
  __hip_atomic_store(p, v, __ATOMIC_RELAXED, __HIP_MEMORY_SCOPE_AGENT);
}

struct BFT {}; struct FPT {};
template<class DT> struct LD;
template<> struct LD<FPT> {
  static __device__ __forceinline__ float get(const void* p, long i) { return ((const float*)p)[i]; }
};
template<> struct LD<BFT> {
  static __device__ __forceinline__ float get(const void* p, long i) { return bf2f(((const unsigned short*)p)[i]); }
};
template<class DT> struct LD4;
template<> struct LD4<FPT> {
  static __device__ __forceinline__ float4 get(const void* p, long i) {
    return *(const float4*)((const float*)p + i);
  }
};
template<> struct LD4<BFT> {
  static __device__ __forceinline__ float4 get(const void* p, long i) {
    ushort4 u = *(const ushort4*)((const unsigned short*)p + i);
    float4 f; f.x = bf2f(u.x); f.y = bf2f(u.y); f.z = bf2f(u.z); f.w = bf2f(u.w); return f;
  }
};
template<class DT> struct ST;
template<> struct ST<FPT> {
  static __device__ __forceinline__ void put(void* p, long i, float v) { ((float*)p)[i] = v; }
};
template<> struct ST<BFT> {
  static __device__ __forceinline__ void put(void* p, long i, float v) { ((unsigned short*)p)[i] = f2bf(v); }
};

// ---- tree grid barrier: 8 groups of 32 -> root -> flag, ALL RELAXED ----
// ws_u[8..15]: group counters, ws_u[16]: root, ws_u[20]: release flag.
// __syncthreads() drains every wave's vmcnt before the leader arrives, so all
// of this WG's sc1 (MALL) stores are globally visible before the counter add.
__device__ __forceinline__ void gbar(unsigned* ws_u, unsigned* ep, int tid, int wg) {
  __syncthreads();
  if (tid == 0) {
    unsigned e = ++(*ep);
    unsigned old = __hip_atomic_fetch_add(&ws_u[8 + (wg >> 5)], 1u,
                                          __ATOMIC_RELAXED, __HIP_MEMORY_SCOPE_AGENT);
    if (old == e * 32u - 1u) {
      unsigned o2 = __hip_atomic_fetch_add(&ws_u[16], 1u,
                                           __ATOMIC_RELAXED, __HIP_MEMORY_SCOPE_AGENT);
      if (o2 == e * 8u - 1u) {
        __hip_atomic_store(&ws_u[20], e, __ATOMIC_RELAXED, __HIP_MEMORY_SCOPE_AGENT);
      }
    }
    while (__hip_atomic_load(&ws_u[20], __ATOMIC_RELAXED, __HIP_MEMORY_SCOPE_AGENT) < e) {
      __builtin_amdgcn_s_sleep(2);
    }
  }
  __syncthreads();
}

// out[t][r] (or [r][t] if TRO) = sum_k W[r*wstride+woff+k] (+ woff2 half if DUAL) * X[t*HD+k] (+biases)
template<class DT, int NR, bool DUAL, bool TRO>
__device__ void gemm_rows(const void* W, int wstride, int woff, int woff2,
                          int r0, const float* X, float* out, int ostride,
                          const void* b1, const void* b2, int tid, float* s_stage) {
  const int PER = NR / 4;
  float acc[PER];
#pragma unroll
  for (int i = 0; i < PER; ++i) acc[i] = 0.f;
  for (int k0 = 0; k0 < HD; k0 += 128) {
    __syncthreads();
    for (int i = tid; i < 64 * 128; i += BLK) {
      int t = i >> 7, kk = i & 127;
      s_stage[t * 129 + kk] = ldw(&X[t * HD + k0 + kk]);
    }
    __syncthreads();
#pragma unroll
    for (int i = 0; i < PER; ++i) {
      int oi = tid + i * BLK;
      int t = oi & 63, r_l = oi >> 6;
      long r = r0 + r_l;
      long wb = r * wstride + woff + k0;
      long wb2 = r * wstride + woff2 + k0;
      float a = 0.f;
#pragma unroll 8
      for (int kk = 0; kk < 128; kk += 4) {
        float4 wv = LD4<DT>::get(W, wb + kk);
        if (DUAL) {
          float4 w2 = LD4<DT>::get(W, wb2 + kk);
          wv.x += w2.x; wv.y += w2.y; wv.z += w2.z; wv.w += w2.w;
        }
        a += wv.x * s_stage[t * 129 + kk]     + wv.y * s_stage[t * 129 + kk + 1]
           + wv.z * s_stage[t * 129 + kk + 2] + wv.w * s_stage[t * 129 + kk + 3];
      }
      acc[i] += a;
    }
  }
  __syncthreads();
#pragma unroll
  for (int i = 0; i < PER; ++i) {
    int oi = tid + i * BLK;
    int t = oi & 63, r_l = oi >> 6;
    int r = r0 + r_l;
    float v = acc[i];
    if (b1) v += LD<DT>::get(b1, r);
    if (b2) v += LD<DT>::get(b2, r);
    if (TRO) stw(&out[r * ostride + t], v); else stw(&out[t * ostride + r], v);
  }
}

template<class DT>
__device__ void run_all(const KArgs& A, int tid, int wg,
                        float* s_big, float* s_red, float* s_w, float* s_m2,
                        float* s_h, float* s_whh, float* s_wh, float* s_gate, float* s_c) {
  float* ws = A.ws;
  unsigned* ws_u = (unsigned*)ws;
  unsigned epoch = 0;
  float* h     = ws + OFF_H;
  float* enc_o = ws + OFF_ENCO;
  float* epT   = ws + OFF_EPT;
  float* WihX  = ws + OFF_WIHX;
  float* Q     = ws + OFF_Q;
  float* M1    = ws + OFF_M1;
  float* M2T   = ws + OFF_M2;
  float* pe_g  = ws + OFF_PE;
  float* H2    = ws + OFF_H2;
  float* PreT  = ws + OFF_PRET;
  float* Xenc  = ws + OFF_XENC;
  float* Xdec  = ws + OFF_XDEC;
  float* pre1  = ws + OFF_PRE1;
  const int j0 = wg * 4;

  // ---- P0a: embedding gathers, zero h/c ----
  if (tid < 4) { s_c[tid] = 0.f; stw(&h[j0 + tid], 0.f); }
  if (wg < 64) {
    int t = wg, tok = A.src[t];
    for (int k = tid; k < HD; k += BLK) stw(&Xenc[t * HD + k], LD<DT>::get(A.enc_emb, (long)tok * HD + k));
  } else if (wg < 128) {
    int t = wg - 64;
    int tok = (t == 0) ? 0 : A.tgt[t - 1];
    for (int k = tid; k < HD; k += BLK) stw(&Xdec[t * HD + k], LD<DT>::get(A.dec_emb, (long)tok * HD + k));
  }
  gbar(ws_u, &epoch, tid, wg);

  // ---- P0b: WihX (enc_Wih@x + bih + bhh), pre1 (W1x@x + w1_b) ----
  gemm_rows<DT, 16, false, false>(A.enc_Wih, 1024, 0, 0, wg * 16, Xenc, WihX, 4096,
                                  A.enc_bih, A.enc_bhh, tid, s_big);
  gemm_rows<DT, 4, false, false>(A.w1_W, 2048, 1024, 0, wg * 4, Xdec, pre1, 1024,
                                 A.w1_b, nullptr, tid, s_big);
  gbar(ws_u, &epoch, tid, wg);

  // ---- encoder loop ----
  const int row_l = tid >> 4, lane = tid & 15;
  const int gg_ = row_l >> 2, qq_ = row_l & 3;
  const int myrow = gg_ * 1024 + j0 + qq_;
  for (int t = 0; t < SL; ++t) {
    const float* hb = h + (t & 1) * HD;
    float* hb2 = h + ((t + 1) & 1) * HD;
    for (int i = tid; i < HD; i += BLK) s_h[i] = ldw(&hb[i]);
    __syncthreads();
    float part = 0.f;
#pragma unroll 4
    for (int j = 0; j < 16; ++j) {
      int k = (lane << 2) + (j << 6);
      float4 wv = LD4<DT>::get(A.enc_Whh, (long)myrow * HD + k);
      const float4 hv = *(const float4*)(s_h + k);
      part += wv.x * hv.x + wv.y * hv.y + wv.z * hv.z + wv.w * hv.w;
    }
    s_red[tid] = part;
    __syncthreads();
    if (tid < 16) {
      float v = 0.f;
      for (int i = 0; i < 16; ++i) v += s_red[tid * 16 + i];
      int rr = (tid >> 2) * 1024 + j0 + (tid & 3);
      s_gate[tid] = v + ldw(&WihX[t * 4096 + rr]);
    }
    __syncthreads();
    if (tid < 4) {
      float ig = s_gate[tid], fg = s_gate[4 + tid], gv = s_gate[8 + tid], og = s_gate[12 + tid];
      float c2 = sigmf(fg) * s_c[tid] + sigmf(ig) * tanhf(gv);
      float h2v = sigmf(og) * tanhf(c2);
      s_c[tid] = c2;
      stw(&hb2[j0 + tid], h2v);
      stw(&enc_o[t * HD + j0 + tid], h2v);
    }
    gbar(ws_u, &epoch, tid, wg);
  }

  // ---- P1ab: epT = (att_Wu@enc_outs + bu)^T ; M1[s][j] = W1c[j].enc_outs[s] ----
  gemm_rows<DT, 4, false, true>(A.att_Wu, 1024, 0, 0, wg * 4, enc_o, epT, 64,
                                A.att_bu, nullptr, tid, s_big);
  gemm_rows<DT, 4, false, false>(A.w1_W, 2048, 0, 0, wg * 4, enc_o, M1, 1024,
                                 nullptr, nullptr, tid, s_big);
  gbar(ws_u, &epoch, tid, wg);

  // ---- P1cd: M2T[s][r] = dec_Wih@M1 ; Q[t][r] = dec_Wih@pre1 + bih + bhh ----
  gemm_rows<DT, 16, false, false>(A.dec_Wih, 1024, 0, 0, wg * 16, M1, M2T, 4096,
                                  nullptr, nullptr, tid, s_big);
  gemm_rows<DT, 16, false, false>(A.dec_Wih, 1024, 0, 0, wg * 16, pre1, Q, 4096,
                                  A.dec_bih, A.dec_bhh, tid, s_big);
  gbar(ws_u, &epoch, tid, wg);

  // ---- P1e: copy my 16 M2 rows into LDS [16][65] ----
  for (int i = tid; i < 1024; i += BLK) {
    int l = i >> 6, s = i & 63;
    int r = (l >> 2) * 1024 + j0 + (l & 3);
    s_m2[l * 65 + s] = ldw(&M2T[s * 4096 + r]);
  }

  // ---- decoder loop ----
  for (int t = 0; t < TL; ++t) {
    const float* hb = h + (t & 1) * HD;
    float* hb2 = h + ((t + 1) & 1) * HD;
    for (int i = tid; i < HD; i += BLK) s_h[i] = ldw(&hb[i]);
    __syncthreads();
    // phase A': Whh@h (all WGs), We@h + partial energies (WGs 0..63)
    {
      float part = 0.f;
#pragma unroll 4
      for (int j = 0; j < 16; ++j) {
        int k = (lane << 2) + (j << 6);
        float4 wv = LD4<DT>::get(A.dec_Whh, (long)myrow * HD + k);
        const float4 hv = *(const float4*)(s_h + k);
        part += wv.x * hv.x + wv.y * hv.y + wv.z * hv.z + wv.w * hv.w;
      }
      s_red[tid] = part;
      __syncthreads();
      if (tid < 16) {
        float v = 0.f;
        for (int i = 0; i < 16; ++i) v += s_red[tid * 16 + i];
        s_whh[tid] = v;
      }
      __syncthreads();
      if (wg < 64) {
        int jr = wg * 16 + row_l;
        float p2 = 0.f;
#pragma unroll 4
        for (int j = 0; j < 16; ++j) {
          int k = (lane << 2) + (j << 6);
          float4 wv = LD4<DT>::get(A.att_We, (long)jr * HD + k);
          const float4 hv = *(const float4*)(s_h + k);
          p2 += wv.x * hv.x + wv.y * hv.y + wv.z * hv.z + wv.w * hv.w;
        }
        s_red[tid] = p2;
        __syncthreads();
        if (tid < 16) {
          float v2 = 0.f;
          for (int i = 0; i < 16; ++i) v2 += s_red[tid * 16 + i];
          s_wh[tid] = v2 + LD<DT>::get(A.att_be, wg * 16 + tid);
        }
        __syncthreads();
        if (tid < 64) {
          int s = tid;
          float pe = 0.f;
#pragma unroll
          for (int jj = 0; jj < 16; ++jj) {
            int jg = wg * 16 + jj;
            float arg = s_wh[jj] + ldw(&epT[jg * 64 + s]);
            pe += LD<DT>::get(A.att_v, jg) * tanhf(arg);
          }
          stw(&pe_g[wg * 64 + s], pe);
        }
      }
    }
    gbar(ws_u, &epoch, tid, wg);
    // phase C: reduce energies, softmax, gates, elementwise
    {
      int s = tid & 63, gb = tid >> 6;
      float pe = 0.f;
      for (int g2 = gb * 16; g2 < gb * 16 + 16; ++g2) pe += ldw(&pe_g[g2 * 64 + s]);
      s_red[tid] = pe;
      __syncthreads();
      if (tid < 64) s_w[tid] = s_red[tid] + s_red[64 + tid] + s_red[128 + tid] + s_red[192 + tid];
      __syncthreads();
      if (tid == 0) {
        float m = s_w[0];
        for (int i = 1; i < 64; ++i) m = fmaxf(m, s_w[i]);
        s_red[0] = m;
      }
      __syncthreads();
      if (tid < 64) s_w[tid] = expf(s_w[tid] - s_red[0]);
      __syncthreads();
      if (tid == 0) {
        float sum = 0.f;
        for (int i = 0; i < 64; ++i) sum += s_w[i];
        s_red[0] = 1.f / sum;
      }
      __syncthreads();
      if (tid < 16) {
        int r = (tid >> 2) * 1024 + j0 + (tid & 3);
        float ctx = 0.f;
#pragma unroll 8
        for (int s2 = 0; s2 < 64; ++s2) ctx += s_m2[tid * 65 + s2] * s_w[s2];
        s_gate[tid] = s_whh[tid] + ldw(&Q[t * 4096 + r]) + ctx * s_red[0];
      }
      __syncthreads();
      if (tid < 4) {
        float ig = s_gate[tid], fg = s_gate[4 + tid], gv = s_gate[8 + tid], og = s_gate[12 + tid];
        float c2 = sigmf(fg) * s_c[tid] + sigmf(ig) * tanhf(gv);
        float h2v = sigmf(og) * tanhf(c2);
        s_c[tid] = c2;
        stw(&hb2[j0 + tid], h2v);
        stw(&H2[t * HD + j0 + tid], h2v);
      }
    }
    gbar(ws_u, &epoch, tid, wg);
  }

  // ---- P2: PreT[j][t] = (w2[:, :H]+w2[:, H:])@H2 + w2_b ----
  gemm_rows<DT, 4, true, true>(A.w2_W, 2048, 0, 1024, wg * 4, H2, PreT, 64,
                               A.w2_b, nullptr, tid, s_big);
  gbar(ws_u, &epoch, tid, wg);

  // ---- P3: logits[t][v] = out_W[v].Pre[t] + out_b[v], contiguous v-range per WG ----
  {
    const int t = tid & 63, kq = tid >> 6;
    const int v0 = wg * 125;
    for (int vg = 0; vg < 5; ++vg) {
      float acc[25];
#pragma unroll
      for (int i = 0; i < 25; ++i) acc[i] = 0.f;
      for (int kc = 0; kc < 8; ++kc) {
        __syncthreads();
        for (int i = tid; i < 128 * 64; i += BLK) {
          int kk = i >> 6, tt = i & 63;
          s_big[kk * 66 + tt] = ldw(&PreT[(kc * 128 + kk) * 64 + tt]);
        }
        __syncthreads();
        float p[32];
#pragma unroll
        for (int k = 0; k < 32; ++k) p[k] = s_big[(kq * 32 + k) * 66 + t];
        for (int i = 0; i < 25; ++i) {
          int v = v0 + vg * 25 + i;
          long wb = (long)v * HD + kc * 128 + kq * 32;
          float a = 0.f;
#pragma unroll
          for (int k = 0; k < 32; k += 4) {
            float4 wv = LD4<DT>::get(A.out_W, wb + k);
            a += wv.x * p[k] + wv.y * p[k + 1] + wv.z * p[k + 2] + wv.w * p[k + 3];
          }
          acc[i] += a;
        }
      }
      __syncthreads();
#pragma unroll
      for (int i = 0; i < 25; ++i) s_big[i * 256 + tid] = acc[i];
      __syncthreads();
      for (int o = tid; o < 1600; o += BLK) {
        int tt = o / 25, i = o - tt * 25;
        int v = v0 + vg * 25 + i;
        float r2 = s_big[i * 256 + tt] + s_big[i * 256 + 64 + tt] + s_big[i * 256 + 128 + tt]
                 + s_big[i * 256 + 192 + tt] + LD<DT>::get(A.out_b, v);
        ST<DT>::put(A.out, (long)tt * VOC + v, r2);
      }
      __syncthreads();
    }
  }
}

__global__ __launch_bounds__(BLK)
void lstm_seq2seq_kernel(KArgs A) {
  __shared__ __align__(16) float s_big[8448];   // gemm stage (64*129) / P3 stage (128*66) / P3 acc (25*256)
  __shared__ float s_red[BLK];
  __shared__ float s_w[64];
  __shared__ float s_m2[16 * 65];
  __shared__ __align__(16) float s_h[HD];
  __shared__ float s_whh[16];
  __shared__ float s_wh[16];
  __shared__ float s_gate[16];
  __shared__ float s_c[4];
  __shared__ int s_flag;

  const int tid = threadIdx.x, wg = blockIdx.x;

  // dtype probe: bf16 pairs -> low-16 bits look like a bf16 with plausible exponent
  {
    const unsigned* pw = (const unsigned*)A.enc_Wih;
    int hits = 0;
    for (int i = tid; i < 4096; i += BLK) {
      unsigned ex = (pw[i] >> 7) & 0xFFu;
      hits += (ex >= 100u && ex <= 126u) ? 1 : 0;
    }
    s_red[tid] = (float)hits;
    __syncthreads();
    for (int s = BLK / 2; s > 0; s >>= 1) {
      if (tid < s) s_red[tid] += s_red[tid + s];
      __syncthreads();
    }
    if (tid == 0) s_flag = (s_red[0] > 2048.0f) ? 1 : 0;
    __syncthreads();
  }

  if (s_flag) run_all<BFT>(A, tid, wg, s_big, s_red, s_w, s_m2, s_h, s_whh, s_wh, s_gate, s_c);
  else        run_all<FPT>(A, tid, wg, s_big, s_red, s_w, s_m2, s_h, s_whh, s_wh, s_gate, s_c);
}

extern "C" void kernel_launch(void* const* d_in, const int* in_sizes, int n_in,
                              void* d_out, int out_size, void* d_ws, size_t ws_size,
                              hipStream_t stream) {
  (void)in_sizes; (void)n_in; (void)out_size; (void)ws_size;
  // zero barrier counters/flag (ws is poisoned 0xAA before every launch)
  hipMemsetAsync(d_ws, 0, 256, stream);
  KArgs a;
  a.src = (const int*)d_in[0];
  a.tgt = (const int*)d_in[1];
  a.enc_emb = d_in[3]; a.enc_Wih = d_in[4]; a.enc_Whh = d_in[5];
  a.enc_bih = d_in[6]; a.enc_bhh = d_in[7];
  a.dec_emb = d_in[8]; a.att_We = d_in[9]; a.att_be = d_in[10];
  a.att_Wu = d_in[11]; a.att_bu = d_in[12]; a.att_v = d_in[13];
  a.w1_W = d_in[14]; a.w1_b = d_in[15]; a.w2_W = d_in[16]; a.w2_b = d_in[17];
  a.dec_Wih = d_in[18]; a.dec_Whh = d_in[19]; a.dec_bih = d_in[20]; a.dec_bhh = d_in[21];
  a.out_W = d_in[22]; a.out_b = d_in[23];
  a.out = d_out; a.ws = (float*)d_ws;
  hipLaunchKernelGGL(lstm_seq2seq_kernel, dim3(NWG), dim3(BLK), 0, stream, a);
}